// Round 6
// baseline (716.679 us; speedup 1.0000x reference)
//
#include <hip/hip_runtime.h>

// ---------------------------------------------------------------------------
// CorefPairScorer: B=4, T=4096, D=768, N=256, HID=200 (padded to 224)
// h1(i,j) = relu(A[i] + Bv[j] + (emb_i*emb_j)@W1bot + b1)
// h2 = relu(h1@W2 + b2); s = h2@W3 + b3; masked softmax rows.
// R6: quarter-pass pair_mlp. Geometry pins the allocator at 128 regs/wave
//     (512 thr + ~57 KB LDS -> 2 blocks/CU -> 4 waves/SIMD -> 2048/4=128),
//     so per-wave live set must fit 128 WITH slack: 1 Mtile x 7 ntiles per
//     pass => acc[7]=28 + bfr[7]=28 + ~30 misc ~= 85 live. embJ gets its own
//     LDS region (staged once); h1 region is 64 rows. No spill expected.
// ---------------------------------------------------------------------------

#define NB 4
#define NN 256
#define DD 768
#define TT 4096
#define HP 224
#define NTILES 14
#define KT1 24
#define KT2 7
#define TRI 136
#define JSTR 776         // embJ LDS row stride (shorts): 2-way bank alias (free)
#define HSTR 232         // h1 LDS row stride (shorts): 2-way bank alias (free)
#define ABS 448          // AB row stride (bf16): [A(224) | B(224)]

typedef __attribute__((ext_vector_type(8))) short short8;
typedef __attribute__((ext_vector_type(4))) float f32x4;

union FragU { uint4 u; short8 s; };

__device__ __forceinline__ float bf2f(unsigned short x) {
    return __uint_as_float(((unsigned int)x) << 16);
}
__device__ __forceinline__ unsigned short f2bf(float f) {
    unsigned int u = __float_as_uint(f);
    u += 0x7fffu + ((u >> 16) & 1u);   // RNE
    return (unsigned short)(u >> 16);
}
__device__ __forceinline__ float blo(unsigned int v) { return __uint_as_float(v << 16); }
__device__ __forceinline__ float bhi(unsigned int v) { return __uint_as_float(v & 0xffff0000u); }
// packed bf16 pair: (a*b) with pre-unpacked b halves; truncating pack via v_perm
__device__ __forceinline__ unsigned int mulpack(unsigned int a, float bl, float bh) {
    unsigned int m0 = __float_as_uint(blo(a) * bl);
    unsigned int m1 = __float_as_uint(bhi(a) * bh);
    return __builtin_amdgcn_perm(m1, m0, 0x07060302u);
}

// ---------------------------------------------------------------------------
// K0 (merged): weight swizzle (blocks 0..2211) + gather/cast (blocks 2212..3235)
//   frag layout: buf[((kt*NT+nt)*64+lane)*8+j] = W[kt*32+(lane>>4)*8+j][nt*16+(lane&15)]
// ---------------------------------------------------------------------------
__global__ void prep_all(const float* __restrict__ W1, const float* __restrict__ W2,
                         const float* __restrict__ ee, const int* __restrict__ eidx,
                         unsigned short* __restrict__ w1n,
                         unsigned short* __restrict__ w1s,
                         unsigned short* __restrict__ w2s,
                         unsigned short* __restrict__ emb) {
    const int N1n = 24 * 28 * 512;   // 344064
    const int N1s = 24 * 14 * 512;   // 172032
    const int N2  = 7 * 14 * 512;    // 50176
    int bx = blockIdx.x;
    if (bx >= 2212) {                 // gather + fp32->bf16
        int g = bx - 2212;
        int b = g >> 8, n = g & 255;
        int t = eidx[b * NN + n];
        const float* src = ee + ((size_t)b * TT + t) * DD;
        unsigned short* dst = emb + ((size_t)b * NN + n) * DD;
        for (int e = threadIdx.x; e < DD; e += 256) dst[e] = f2bf(src[e]);
        return;
    }
    int idx = bx * 256 + threadIdx.x;
    if (idx < N1n) {
        int j = idx & 7, lane = (idx >> 3) & 63, f = idx >> 9;
        int nt = f % 28, kt = f / 28;
        int k = kt * 32 + (lane >> 4) * 8 + j;     // 0..767
        int n = nt * 16 + (lane & 15);             // 0..447
        float v;
        if (n < HP) v = (n < 200) ? W1[(size_t)k * 200 + n] : 0.f;
        else { int c2 = n - HP; v = (c2 < 200) ? W1[(size_t)(768 + k) * 200 + c2] : 0.f; }
        w1n[idx] = f2bf(v);
    } else if (idx < N1n + N1s) {
        int i2 = idx - N1n;
        int j = i2 & 7, lane = (i2 >> 3) & 63, f = i2 >> 9;
        int nt = f % NTILES, kt = f / NTILES;
        int k = kt * 32 + (lane >> 4) * 8 + j;
        int n = nt * 16 + (lane & 15);
        float v = (n < 200) ? W1[(size_t)(1536 + k) * 200 + n] : 0.f;
        w1s[i2] = f2bf(v);
    } else if (idx < N1n + N1s + N2) {
        int i2 = idx - N1n - N1s;
        int j = i2 & 7, lane = (i2 >> 3) & 63, f = i2 >> 9;
        int nt = f % NTILES, kt = f / NTILES;
        int k = kt * 32 + (lane >> 4) * 8 + j;
        int n = nt * 16 + (lane & 15);
        float v = (k < 200 && n < 200) ? W2[(size_t)k * 200 + n] : 0.f;
        w2s[i2] = f2bf(v);
    }
}

// ---------------------------------------------------------------------------
// K2: AB = emb(1024x768) @ [W1top|W1mid](768x448), bf16 MFMA, bf16 out.
//   64 blocks x 256 thr (4 waves). Wave: 1 Mtile (16 rows) x 7 ntiles.
// ---------------------------------------------------------------------------
__global__ __launch_bounds__(256)
void node_mfma(const unsigned short* __restrict__ emb,
               const unsigned short* __restrict__ w1n,
               unsigned short* __restrict__ AB) {
    int tid = threadIdx.x, lane = tid & 63, w = tid >> 6;
    int q = lane >> 4, c = lane & 15;
    int mt = w >> 1;
    int ng = ((blockIdx.x & 1) << 1) | (w & 1);     // 0..3 -> 7 ntiles each
    int m0 = (blockIdx.x >> 1) * 32 + mt * 16;
    const uint4* ga = (const uint4*)emb + (size_t)(m0 + c) * 96;
    const uint4* gb = (const uint4*)w1n;

    f32x4 acc[7];
#pragma unroll
    for (int n = 0; n < 7; ++n) acc[n] = (f32x4){0.f, 0.f, 0.f, 0.f};

    for (int kt = 0; kt < KT1; ++kt) {
        FragU a; a.u = ga[kt * 4 + q];
#pragma unroll
        for (int n = 0; n < 7; ++n) {
            FragU bb; bb.u = gb[((kt * 28 + ng * 7 + n) << 6) + lane];
            acc[n] = __builtin_amdgcn_mfma_f32_16x16x32_bf16(a.s, bb.s, acc[n], 0, 0, 0);
        }
    }
#pragma unroll
    for (int n = 0; n < 7; ++n) {
        int col = (ng * 7 + n) * 16 + c;
#pragma unroll
        for (int rr = 0; rr < 4; ++rr)
            AB[(size_t)(m0 + q * 4 + rr) * ABS + col] = f2bf(acc[n][rr]);
    }
}

// ---------------------------------------------------------------------------
// K3: fused pair MLP per 16x16 (i,j) tile. 512 threads = 8 waves.
//   4 quarter-passes of 64 pair-rows (4 Mtiles). Wave (mg,nh): Mtile mg of
//   the quarter, ntile half nh. Phase1 acc[7] -> epilogue -> h1(64xHSTR) in
//   LDS -> phase2 acc2[7] -> phase3 reduce. embJ staged once (own region).
// ---------------------------------------------------------------------------
__global__ __launch_bounds__(512)
void pair_mlp(
    const unsigned short* __restrict__ emb,
    const unsigned short* __restrict__ w1s,
    const unsigned short* __restrict__ w2s,
    const unsigned short* __restrict__ AB,
    const float* __restrict__ b1, const float* __restrict__ b2,
    const float* __restrict__ W3, const float* __restrict__ b3,
    float* __restrict__ S) {
    int z = blockIdx.x;
    int b = z / TRI;
    int r = z % TRI;
    int ti = (int)((sqrtf(8.f * (float)r + 1.f) - 1.f) * 0.5f);
    while ((ti + 1) * (ti + 2) / 2 <= r) ++ti;
    while (ti * (ti + 1) / 2 > r) --ti;
    int tj = r - ti * (ti + 1) / 2;
    int i0 = ti << 4, j0 = tj << 4;

    int tid = threadIdx.x;
    int lane = tid & 63;
    int w = tid >> 6;
    int q = lane >> 4, c = lane & 15;
    int mg = w >> 1, nh = w & 1;          // mg 0..3 (Mtile in quarter), nh 0..1

    __shared__ unsigned short smJ[16 * JSTR];   // 24832 B, embJ staged once
    __shared__ unsigned short smH[64 * HSTR];   // 29696 B, h1 quarter
    __shared__ float sred[2][256];              //  2048 B

    const uint4* w1f = (const uint4*)w1s;
    const uint4* w2f = (const uint4*)w2s;
    const uint4* gI  = (const uint4*)(emb + ((size_t)b * NN + i0) * DD);
    const uint4* gJ  = (const uint4*)(emb + ((size_t)b * NN + j0) * DD);

    // ---- stage embJ (16 rows x 768 bf16, stride 776) once ----
#pragma unroll
    for (int k = 0; k < 3; ++k) {
        int c2 = tid + 512 * k;            // 0..1535
        int row = c2 / 96, col = c2 - row * 96;
        uint4 v = gJ[row * 96 + col];
        *(uint4*)(&smJ[row * JSTR + col * 8]) = v;
    }
    __syncthreads();

    for (int qtr = 0; qtr < 4; ++qtr) {
        int tg = (qtr << 2) + mg;          // global Mtile (== ii offset), 0..15

        // ---- phase 1: acc[7] over K=768 ----
        f32x4 acc[7];
#pragma unroll
        for (int n = 0; n < 7; ++n) acc[n] = (f32x4){0.f, 0.f, 0.f, 0.f};

        for (int kt = 0; kt < KT1; ++kt) {
            uint4 bfr[7];
#pragma unroll
            for (int n = 0; n < 7; ++n)
                bfr[n] = w1f[(kt * NTILES + nh * 7 + n) * 64 + lane];
            uint4 ej = *(const uint4*)(&smJ[c * JSTR + kt * 32 + q * 8]);
            uint4 ei = gI[tg * 96 + kt * 4 + q];    // quad-broadcast (L1)
            FragU a;
            a.u.x = mulpack(ei.x, blo(ej.x), bhi(ej.x));
            a.u.y = mulpack(ei.y, blo(ej.y), bhi(ej.y));
            a.u.z = mulpack(ei.z, blo(ej.z), bhi(ej.z));
            a.u.w = mulpack(ei.w, blo(ej.w), bhi(ej.w));
#pragma unroll
            for (int n = 0; n < 7; ++n) {
                FragU bb; bb.u = bfr[n];
                acc[n] = __builtin_amdgcn_mfma_f32_16x16x32_bf16(a.s, bb.s, acc[n], 0, 0, 0);
            }
        }

        // ---- epilogue: h1 = relu(acc + A[i] + Bv[j] + b1) -> smH bf16 ----
        __syncthreads();   // prev quarter's phase-2 readers done
#pragma unroll
        for (int n = 0; n < 7; ++n) {
            int h = ((nh * 7 + n) << 4) + c;
            float aI = bf2f(AB[(size_t)(b * NN + i0 + tg) * ABS + h]);
            float base = aI + ((h < 200) ? b1[h] : 0.f);
#pragma unroll
            for (int rr = 0; rr < 4; ++rr) {
                float v = acc[n][rr] + base +
                          bf2f(AB[(size_t)(b * NN + j0 + q * 4 + rr) * ABS + HP + h]);
                v = fmaxf(v, 0.f);
                smH[((mg << 4) + q * 4 + rr) * HSTR + h] = f2bf(v);
            }
        }
        __syncthreads();

        // ---- phase 2: wave's Mtile (16 pairs), K=224 (7 ktiles) ----
        f32x4 acc2[7];
#pragma unroll
        for (int n = 0; n < 7; ++n) acc2[n] = (f32x4){0.f, 0.f, 0.f, 0.f};

        for (int kk = 0; kk < KT2; ++kk) {
            uint4 bfr2[7];
#pragma unroll
            for (int n = 0; n < 7; ++n)
                bfr2[n] = w2f[(kk * NTILES + nh * 7 + n) * 64 + lane];
            FragU a2;
            a2.u = *(const uint4*)(&smH[((mg << 4) + c) * HSTR + kk * 32 + q * 8]);
#pragma unroll
            for (int n = 0; n < 7; ++n) {
                FragU bb; bb.u = bfr2[n];
                acc2[n] = __builtin_amdgcn_mfma_f32_16x16x32_bf16(a2.s, bb.s, acc2[n], 0, 0, 0);
            }
        }

        // ---- phase 3: s = relu(h2 + b2) . W3, reduce 16 cols via shfl ----
#pragma unroll
        for (int rr = 0; rr < 4; ++rr) {
            float part = 0.f;
#pragma unroll
            for (int n = 0; n < 7; ++n) {
                int h = ((nh * 7 + n) << 4) + c;
                float b2v = (h < 200) ? b2[h] : 0.f;
                float w3v = (h < 200) ? W3[h] : 0.f;
                float hv = fmaxf(acc2[n][rr] + b2v, 0.f);
                part += hv * w3v;
            }
            part += __shfl_xor(part, 1);
            part += __shfl_xor(part, 2);
            part += __shfl_xor(part, 4);
            part += __shfl_xor(part, 8);
            if (c == 0) {
                int p = (qtr << 6) + (mg << 4) + q * 4 + rr;
                sred[nh][p] = part;
            }
        }
    }
    __syncthreads();
    if (tid < 256) {
        int ii = tid >> 4, jj = tid & 15;
        float s = sred[0][tid] + sred[1][tid] + b3[0];
        S[((size_t)b * NN + i0 + ii) * NN + j0 + jj] = s;
    }
}

// ---------------------------------------------------------------------------
// K4: masked softmax per row; diag logit = 0; invalid -> -1000
// ---------------------------------------------------------------------------
__global__ __launch_bounds__(256) void softmax_rows(const float* __restrict__ S,
                                                    float* __restrict__ out) {
    int b = blockIdx.x >> 8, i = blockIdx.x & 255;
    int j = threadIdx.x;
    int lane = j & 63, w = j >> 6;
    __shared__ float red[16];
    float x = (j < i) ? S[((size_t)b * NN + i) * NN + j] : ((j == i) ? 0.f : -1e30f);
    float m = x;
#pragma unroll
    for (int off = 32; off; off >>= 1) m = fmaxf(m, __shfl_xor(m, off));
    if (lane == 0) red[w] = m;
    __syncthreads();
    float mx = fmaxf(fmaxf(red[0], red[1]), fmaxf(red[2], red[3]));
    float e = (j <= i) ? __expf(x - mx) : 0.f;
    float s = e;
#pragma unroll
    for (int off = 32; off; off >>= 1) s += __shfl_xor(s, off);
    if (lane == 0) red[8 + w] = s;
    __syncthreads();
    float sum = red[8] + red[9] + red[10] + red[11];
    out[((size_t)b * NN + i) * NN + j] = (j <= i) ? (e / sum) : -1000.0f;
}

// ---------------------------------------------------------------------------
extern "C" void kernel_launch(void* const* d_in, const int* in_sizes, int n_in,
                              void* d_out, int out_size, void* d_ws, size_t ws_size,
                              hipStream_t stream) {
    const float* ee  = (const float*)d_in[0];
    const int*   eidx = (const int*)d_in[1];
    const float* W1  = (const float*)d_in[2];
    const float* b1  = (const float*)d_in[3];
    const float* W2  = (const float*)d_in[4];
    const float* b2  = (const float*)d_in[5];
    const float* W3  = (const float*)d_in[6];
    const float* b3  = (const float*)d_in[7];
    float* out = (float*)d_out;

    char* p = (char*)d_ws;
    unsigned short* emb = (unsigned short*)p; p += (size_t)NB * NN * DD * 2;       // 1.5 MB
    unsigned short* w1n = (unsigned short*)p; p += (size_t)24 * 28 * 512 * 2;      // 672 KB
    unsigned short* w1s = (unsigned short*)p; p += (size_t)24 * 14 * 512 * 2;      // 336 KB
    unsigned short* w2s = (unsigned short*)p; p += (size_t)7 * 14 * 512 * 2;       // 98 KB
    unsigned short* AB  = (unsigned short*)p; p += (size_t)NB * NN * ABS * 2;      // 896 KB
    float* S  = (float*)p; p += (size_t)NB * NN * NN * 4;                           // 1 MB

    prep_all<<<3236, 256, 0, stream>>>(W1, W2, ee, eidx, w1n, w1s, w2s, emb);
    node_mfma<<<64, 256, 0, stream>>>(emb, w1n, AB);
    pair_mlp<<<NB * TRI, 512, 0, stream>>>(emb, w1s, w2s, AB, b1, b2, W3, b3, S);
    softmax_rows<<<NB * NN, 256, 0, stream>>>(S, out);
}

// Round 7
// 324.701 us; speedup vs baseline: 2.2072x; 2.2072x over previous
//
#include <hip/hip_runtime.h>

// ---------------------------------------------------------------------------
// CorefPairScorer: B=4, T=4096, D=768, N=256, HID=200 (padded to 224)
// h1(i,j) = relu(A[i] + Bv[j] + (emb_i*emb_j)@W1bot + b1)
// h2 = relu(h1@W2 + b2); s = h2@W3 + b3; masked softmax rows.
// R7: spill site was the EPILOGUE (35 scalar global AB loads co-live with
//     acc => per-pass acc dump, ~0.2 MB/block scratch). Fix: stage Ai and
//     Bv+b1 tiles in LDS once per block; epilogue = ds_read_u16 only.
//     Also: h1 stored frag-packed (zero-conflict b128), embJ read from
//     global (drops the 8-way-conflict smJ), 256-thr blocks with
//     acc[2][7] per wave (R=2 reuse of W1 fragments).
// ---------------------------------------------------------------------------

#define NB 4
#define NN 256
#define DD 768
#define TT 4096
#define HP 224
#define NTILES 14
#define KT1 24
#define KT2 7
#define TRI 136
#define ABS 448          // AB row stride (bf16): [A(224) | B(224)]
#define MTS 3584         // shorts per packed Mtile (16 rows x 224)

typedef __attribute__((ext_vector_type(8))) short short8;
typedef __attribute__((ext_vector_type(4))) float f32x4;

union FragU { uint4 u; short8 s; };

__device__ __forceinline__ float bf2f(unsigned short x) {
    return __uint_as_float(((unsigned int)x) << 16);
}
__device__ __forceinline__ unsigned short f2bf(float f) {
    unsigned int u = __float_as_uint(f);
    u += 0x7fffu + ((u >> 16) & 1u);   // RNE
    return (unsigned short)(u >> 16);
}
__device__ __forceinline__ float blo(unsigned int v) { return __uint_as_float(v << 16); }
__device__ __forceinline__ float bhi(unsigned int v) { return __uint_as_float(v & 0xffff0000u); }
// packed bf16 pair: (a*b) with pre-unpacked b halves; truncating pack via v_perm
__device__ __forceinline__ unsigned int mulpack(unsigned int a, float bl, float bh) {
    unsigned int m0 = __float_as_uint(blo(a) * bl);
    unsigned int m1 = __float_as_uint(bhi(a) * bh);
    return __builtin_amdgcn_perm(m1, m0, 0x07060302u);
}

// ---------------------------------------------------------------------------
// K0 (merged): weight swizzle (blocks 0..2211) + gather/cast (blocks 2212..3235)
//   frag layout: buf[((kt*NT+nt)*64+lane)*8+j] = W[kt*32+(lane>>4)*8+j][nt*16+(lane&15)]
// ---------------------------------------------------------------------------
__global__ void prep_all(const float* __restrict__ W1, const float* __restrict__ W2,
                         const float* __restrict__ ee, const int* __restrict__ eidx,
                         unsigned short* __restrict__ w1n,
                         unsigned short* __restrict__ w1s,
                         unsigned short* __restrict__ w2s,
                         unsigned short* __restrict__ emb) {
    const int N1n = 24 * 28 * 512;   // 344064
    const int N1s = 24 * 14 * 512;   // 172032
    const int N2  = 7 * 14 * 512;    // 50176
    int bx = blockIdx.x;
    if (bx >= 2212) {                 // gather + fp32->bf16
        int g = bx - 2212;
        int b = g >> 8, n = g & 255;
        int t = eidx[b * NN + n];
        const float* src = ee + ((size_t)b * TT + t) * DD;
        unsigned short* dst = emb + ((size_t)b * NN + n) * DD;
        for (int e = threadIdx.x; e < DD; e += 256) dst[e] = f2bf(src[e]);
        return;
    }
    int idx = bx * 256 + threadIdx.x;
    if (idx < N1n) {
        int j = idx & 7, lane = (idx >> 3) & 63, f = idx >> 9;
        int nt = f % 28, kt = f / 28;
        int k = kt * 32 + (lane >> 4) * 8 + j;     // 0..767
        int n = nt * 16 + (lane & 15);             // 0..447
        float v;
        if (n < HP) v = (n < 200) ? W1[(size_t)k * 200 + n] : 0.f;
        else { int c2 = n - HP; v = (c2 < 200) ? W1[(size_t)(768 + k) * 200 + c2] : 0.f; }
        w1n[idx] = f2bf(v);
    } else if (idx < N1n + N1s) {
        int i2 = idx - N1n;
        int j = i2 & 7, lane = (i2 >> 3) & 63, f = i2 >> 9;
        int nt = f % NTILES, kt = f / NTILES;
        int k = kt * 32 + (lane >> 4) * 8 + j;
        int n = nt * 16 + (lane & 15);
        float v = (n < 200) ? W1[(size_t)(1536 + k) * 200 + n] : 0.f;
        w1s[i2] = f2bf(v);
    } else if (idx < N1n + N1s + N2) {
        int i2 = idx - N1n - N1s;
        int j = i2 & 7, lane = (i2 >> 3) & 63, f = i2 >> 9;
        int nt = f % NTILES, kt = f / NTILES;
        int k = kt * 32 + (lane >> 4) * 8 + j;
        int n = nt * 16 + (lane & 15);
        float v = (k < 200 && n < 200) ? W2[(size_t)k * 200 + n] : 0.f;
        w2s[i2] = f2bf(v);
    }
}

// ---------------------------------------------------------------------------
// K2: AB = emb(1024x768) @ [W1top|W1mid](768x448), bf16 MFMA, bf16 out.
// ---------------------------------------------------------------------------
__global__ __launch_bounds__(256)
void node_mfma(const unsigned short* __restrict__ emb,
               const unsigned short* __restrict__ w1n,
               unsigned short* __restrict__ AB) {
    int tid = threadIdx.x, lane = tid & 63, w = tid >> 6;
    int q = lane >> 4, c = lane & 15;
    int mt = w >> 1;
    int ng = ((blockIdx.x & 1) << 1) | (w & 1);
    int m0 = (blockIdx.x >> 1) * 32 + mt * 16;
    const uint4* ga = (const uint4*)emb + (size_t)(m0 + c) * 96;
    const uint4* gb = (const uint4*)w1n;

    f32x4 acc[7];
#pragma unroll
    for (int n = 0; n < 7; ++n) acc[n] = (f32x4){0.f, 0.f, 0.f, 0.f};

    for (int kt = 0; kt < KT1; ++kt) {
        FragU a; a.u = ga[kt * 4 + q];
#pragma unroll
        for (int n = 0; n < 7; ++n) {
            FragU bb; bb.u = gb[((kt * 28 + ng * 7 + n) << 6) + lane];
            acc[n] = __builtin_amdgcn_mfma_f32_16x16x32_bf16(a.s, bb.s, acc[n], 0, 0, 0);
        }
    }
#pragma unroll
    for (int n = 0; n < 7; ++n) {
        int col = (ng * 7 + n) * 16 + c;
#pragma unroll
        for (int rr = 0; rr < 4; ++rr)
            AB[(size_t)(m0 + q * 4 + rr) * ABS + col] = f2bf(acc[n][rr]);
    }
}

// ---------------------------------------------------------------------------
// K3: fused pair MLP per 16x16 (i,j) tile. 256 threads = 4 waves.
//   4 passes of 4 Mtiles. Wave (mp = w>>1, nh = w&1): Mtiles {2mp,2mp+1},
//   ntile-half nh. Phase1 acc[2][7] (embJ/embI direct from global, product
//   via mulpack, W1 frags global). Epilogue: +Ai +Bv(+b1) from LDS (staged
//   once) -> h1 frag-packed in smH. Phase2 acc2[2][7] from smH b128 (zero
//   conflict). Phase3 shfl reduce -> sred -> S.
// ---------------------------------------------------------------------------
__global__ __launch_bounds__(256)
void pair_mlp(
    const unsigned short* __restrict__ emb,
    const unsigned short* __restrict__ w1s,
    const unsigned short* __restrict__ w2s,
    const unsigned short* __restrict__ AB,
    const float* __restrict__ b1, const float* __restrict__ b2,
    const float* __restrict__ W3, const float* __restrict__ b3,
    float* __restrict__ S) {
    int z = blockIdx.x;
    int b = z / TRI;
    int r = z % TRI;
    int ti = (int)((sqrtf(8.f * (float)r + 1.f) - 1.f) * 0.5f);
    while ((ti + 1) * (ti + 2) / 2 <= r) ++ti;
    while (ti * (ti + 1) / 2 > r) --ti;
    int tj = r - ti * (ti + 1) / 2;
    int i0 = ti << 4, j0 = tj << 4;

    int tid = threadIdx.x;
    int lane = tid & 63;
    int w = tid >> 6;                 // 0..3
    int q = lane >> 4, c = lane & 15;
    int mp = w >> 1, nh = w & 1;      // mp 0..1 (Mtile pair), nh 0..1

    __shared__ unsigned short smH[4 * MTS];   // 28672 B: h1, frag-packed, 4 Mtiles
    __shared__ unsigned short Ai[16 * HP];    //  7168 B: A[i]-rows
    __shared__ unsigned short Bv[16 * HP];    //  7168 B: Bv[j]-rows + b1
    __shared__ float sred[2][256];            //  2048 B

    // ---- stage Ai / (Bv + b1) tiles (bf16) ----
    for (int m = 0; m < 16; ++m) {
        for (int h = tid; h < HP; h += 256) {
            Ai[m * HP + h] = AB[(size_t)(b * NN + i0 + m) * ABS + h];
            float bv = bf2f(AB[(size_t)(b * NN + j0 + m) * ABS + HP + h]) +
                       ((h < 200) ? b1[h] : 0.f);
            Bv[m * HP + h] = f2bf(bv);
        }
    }
    __syncthreads();

    const uint4* w1f = (const uint4*)w1s;
    const uint4* w2f = (const uint4*)w2s;
    const uint4* gI  = (const uint4*)(emb + ((size_t)b * NN + i0) * DD);
    const uint4* gJc = (const uint4*)(emb + ((size_t)b * NN + j0 + c) * DD); // per-lane row

    for (int pass = 0; pass < 4; ++pass) {
        // ---- phase 1: acc[2][7] over K=768 ----
        f32x4 acc[2][7];
#pragma unroll
        for (int t = 0; t < 2; ++t)
#pragma unroll
            for (int n = 0; n < 7; ++n)
                acc[t][n] = (f32x4){0.f, 0.f, 0.f, 0.f};

        for (int kt = 0; kt < KT1; ++kt) {
            uint4 bfr[7];
#pragma unroll
            for (int n = 0; n < 7; ++n)
                bfr[n] = w1f[(kt * NTILES + nh * 7 + n) * 64 + lane];
            uint4 ej = gJc[kt * 4 + q];         // embJ row j0+c (L1-resident)
            float exl = blo(ej.x), exh = bhi(ej.x);
            float eyl = blo(ej.y), eyh = bhi(ej.y);
            float ezl = blo(ej.z), ezh = bhi(ej.z);
            float ewl = blo(ej.w), ewh = bhi(ej.w);
#pragma unroll
            for (int t = 0; t < 2; ++t) {
                int tg = (pass << 2) + (mp << 1) + t;   // global Mtile (i offset)
                uint4 ei = gI[tg * 96 + kt * 4 + q];    // quad-broadcast
                FragU a;
                a.u.x = mulpack(ei.x, exl, exh);
                a.u.y = mulpack(ei.y, eyl, eyh);
                a.u.z = mulpack(ei.z, ezl, ezh);
                a.u.w = mulpack(ei.w, ewl, ewh);
#pragma unroll
                for (int n = 0; n < 7; ++n) {
                    FragU bb; bb.u = bfr[n];
                    acc[t][n] = __builtin_amdgcn_mfma_f32_16x16x32_bf16(a.s, bb.s, acc[t][n], 0, 0, 0);
                }
            }
        }

        // ---- epilogue: h1 = relu(acc + Ai + Bv) -> smH (frag-packed bf16) ----
#pragma unroll
        for (int t = 0; t < 2; ++t) {
            int tg = (pass << 2) + (mp << 1) + t;
            int lt = (mp << 1) + t;                     // Mtile slot in smH
#pragma unroll
            for (int n = 0; n < 7; ++n) {
                int h = ((nh * 7 + n) << 4) + c;
                float base = bf2f(Ai[tg * HP + h]);
                int kk2 = h >> 5, q2 = (h >> 3) & 3, j2 = h & 7;
                int fa = lt * MTS + ((kk2 * 4 + q2) << 7) + j2;   // + c2*8 below
#pragma unroll
                for (int rr = 0; rr < 4; ++rr) {
                    float v = acc[t][n][rr] + base + bf2f(Bv[(q * 4 + rr) * HP + h]);
                    v = fmaxf(v, 0.f);
                    smH[fa + ((q * 4 + rr) << 3)] = f2bf(v);
                }
            }
        }
        __syncthreads();

        // ---- phase 2: acc2[2][7] over K=224 from packed smH ----
        f32x4 acc2[2][7];
#pragma unroll
        for (int u = 0; u < 2; ++u)
#pragma unroll
            for (int n = 0; n < 7; ++n)
                acc2[u][n] = (f32x4){0.f, 0.f, 0.f, 0.f};

        for (int kk = 0; kk < KT2; ++kk) {
            uint4 bfr2[7];
#pragma unroll
            for (int n = 0; n < 7; ++n)
                bfr2[n] = w2f[(kk * NTILES + nh * 7 + n) * 64 + lane];
#pragma unroll
            for (int u = 0; u < 2; ++u) {
                int lt = (mp << 1) + u;
                FragU a2;
                a2.u = *(const uint4*)(&smH[lt * MTS + (((kk * 4 + q) * 16 + c) << 3)]);
#pragma unroll
                for (int n = 0; n < 7; ++n) {
                    FragU bb; bb.u = bfr2[n];
                    acc2[u][n] = __builtin_amdgcn_mfma_f32_16x16x32_bf16(a2.s, bb.s, acc2[u][n], 0, 0, 0);
                }
            }
        }

        // ---- phase 3: s = relu(h2 + b2) . W3, reduce cols via shfl ----
#pragma unroll
        for (int u = 0; u < 2; ++u) {
#pragma unroll
            for (int rr = 0; rr < 4; ++rr) {
                float part = 0.f;
#pragma unroll
                for (int n = 0; n < 7; ++n) {
                    int h = ((nh * 7 + n) << 4) + c;
                    float b2v = (h < 200) ? b2[h] : 0.f;
                    float w3v = (h < 200) ? W3[h] : 0.f;
                    float hv = fmaxf(acc2[u][n][rr] + b2v, 0.f);
                    part += hv * w3v;
                }
                part += __shfl_xor(part, 1);
                part += __shfl_xor(part, 2);
                part += __shfl_xor(part, 4);
                part += __shfl_xor(part, 8);
                if (c == 0) {
                    int p = (pass << 6) + (((mp << 1) + u) << 4) + q * 4 + rr;
                    sred[nh][p] = part;
                }
            }
        }
        __syncthreads();
    }

    {   // final: S[b][i0+ii][j0+jj]
        int ii = tid >> 4, jj = tid & 15;
        float s = sred[0][tid] + sred[1][tid] + b3[0];
        S[((size_t)b * NN + i0 + ii) * NN + j0 + jj] = s;
    }
}

// ---------------------------------------------------------------------------
// K4: masked softmax per row; diag logit = 0; invalid -> -1000
// ---------------------------------------------------------------------------
__global__ __launch_bounds__(256) void softmax_rows(const float* __restrict__ S,
                                                    float* __restrict__ out) {
    int b = blockIdx.x >> 8, i = blockIdx.x & 255;
    int j = threadIdx.x;
    int lane = j & 63, w = j >> 6;
    __shared__ float red[16];
    float x = (j < i) ? S[((size_t)b * NN + i) * NN + j] : ((j == i) ? 0.f : -1e30f);
    float m = x;
#pragma unroll
    for (int off = 32; off; off >>= 1) m = fmaxf(m, __shfl_xor(m, off));
    if (lane == 0) red[w] = m;
    __syncthreads();
    float mx = fmaxf(fmaxf(red[0], red[1]), fmaxf(red[2], red[3]));
    float e = (j <= i) ? __expf(x - mx) : 0.f;
    float s = e;
#pragma unroll
    for (int off = 32; off; off >>= 1) s += __shfl_xor(s, off);
    if (lane == 0) red[8 + w] = s;
    __syncthreads();
    float sum = red[8] + red[9] + red[10] + red[11];
    out[((size_t)b * NN + i) * NN + j] = (j <= i) ? (e / sum) : -1000.0f;
}

// ---------------------------------------------------------------------------
extern "C" void kernel_launch(void* const* d_in, const int* in_sizes, int n_in,
                              void* d_out, int out_size, void* d_ws, size_t ws_size,
                              hipStream_t stream) {
    const float* ee  = (const float*)d_in[0];
    const int*   eidx = (const int*)d_in[1];
    const float* W1  = (const float*)d_in[2];
    const float* b1  = (const float*)d_in[3];
    const float* W2  = (const float*)d_in[4];
    const float* b2  = (const float*)d_in[5];
    const float* W3  = (const float*)d_in[6];
    const float* b3  = (const float*)d_in[7];
    float* out = (float*)d_out;

    char* p = (char*)d_ws;
    unsigned short* emb = (unsigned short*)p; p += (size_t)NB * NN * DD * 2;       // 1.5 MB
    unsigned short* w1n = (unsigned short*)p; p += (size_t)24 * 28 * 512 * 2;      // 672 KB
    unsigned short* w1s = (unsigned short*)p; p += (size_t)24 * 14 * 512 * 2;      // 336 KB
    unsigned short* w2s = (unsigned short*)p; p += (size_t)7 * 14 * 512 * 2;       // 98 KB
    unsigned short* AB  = (unsigned short*)p; p += (size_t)NB * NN * ABS * 2;      // 896 KB
    float* S  = (float*)p; p += (size_t)NB * NN * NN * 4;                           // 1 MB

    prep_all<<<3236, 256, 0, stream>>>(W1, W2, ee, eidx, w1n, w1s, w2s, emb);
    node_mfma<<<64, 256, 0, stream>>>(emb, w1n, AB);
    pair_mlp<<<NB * TRI, 256, 0, stream>>>(emb, w1s, w2s, AB, b1, b2, W3, b3, S);
    softmax_rows<<<NB * NN, 256, 0, stream>>>(S, out);
}